// Round 12
// baseline (131.084 us; speedup 1.0000x reference)
//
#include <hip/hip_runtime.h>
#include <math.h>

// Problem dims (fixed by the reference setup): B=4, C=64, H=512, W=512, fp32.
#define HH 512
#define W4Q 128          // float4 quads per row
#define IMG (HH * 512)
#define NR 64            // LDS ring: 64 row slots (pow2)
#define RST 129          // quads per slot (+1 pad -> odd stride, conflict-free)
#define SS 16            // rows per step (write slots disjoint from read span)
#define HALF 256         // output rows per block
#define NSTEP (HALF / SS)   // 16

typedef float f32x4 __attribute__((ext_vector_type(4)));

__device__ __forceinline__ f32x4 bc4(float v) { f32x4 r = {v, v, v, v}; return r; }
__device__ __forceinline__ float softplus(float x) {
    return fmaxf(x, 0.0f) + log1pf(expf(-fabsf(x)));
}

__global__ __launch_bounds__(512) void lap3_kernel(const float* __restrict__ u,
                                                   const float* __restrict__ D,
                                                   float* __restrict__ out) {
    // 132 KB rolling row window (64 rows x 129 quads). One block per CU.
    __shared__ f32x4 lds[NR * RST];

    const int b    = blockIdx.x;        // 512 blocks = 256 images x 2 halves
    const int bc   = b >> 1;            // image index (b*64 + c)
    const int row0 = (b & 1) * HALF;    // output rows [row0, row0+256)
    const int c    = bc & 63;

    const float s0 = softplus(D[c]);
    const float s1 = softplus(D[64 + c]);
    const float s2 = softplus(D[128 + c]);
    const float m4c = -4.0f * (s0 + s1 + s2);

    const int t    = threadIdx.x;
    const int q    = t & 127;           // compute: quad column
    const int g    = t >> 7;            // compute: row group 0..3 (4 rows each)
    const int lane = t & 63;            // lane within wave
    const int wave = t >> 6;            // 0..7
    const int hh   = wave & 1;          // staging: which 64-quad half-row
    const int wr   = wave >> 1;         // staging: row subgroup 0..3

    const f32x4* __restrict__ img4 =
        reinterpret_cast<const f32x4*>(u) + (size_t)bc * (IMG / 4);
    f32x4* __restrict__ out4 =
        reinterpret_cast<f32x4*>(out) + (size_t)bc * (IMG / 4);

    // per-lane global column base for direct-to-LDS staging
    const f32x4* gbase = img4 + hh * 64 + lane;

    // Direct global->LDS DMA: wave-uniform LDS base + lane*16B (linear layout;
    // the +1-quad pad lives at the END of each slot so halves stay contiguous).
#define STAGE_ROW(vrow_)                                                        \
    do {                                                                        \
        const int vr_ = (vrow_);                                                \
        const int cr_ = min(max(vr_, 0), HH - 1);                               \
        const int sl_ = vr_ & (NR - 1);                                         \
        __builtin_amdgcn_global_load_lds(                                       \
            (const __attribute__((address_space(1))) void*)(gbase + cr_ * W4Q), \
            (__attribute__((address_space(3))) void*)&lds[sl_ * RST + hh * 64], \
            16, 0, 0);                                                          \
    } while (0)

    // ---- prologue: stage virtual rows [row0-16, row0+32) (48 rows, clamped).
#pragma unroll
    for (int j = 0; j < 12; ++j)
        STAGE_ROW(row0 - 16 + wr + 4 * j);
    asm volatile("s_waitcnt vmcnt(0)" ::: "memory");
    __builtin_amdgcn_s_barrier();
    asm volatile("" ::: "memory");

    // horizontal boundary handling (validated R4/R7 scheme)
    const int qm1 = max(q - 1, 0), qp1 = min(q + 1, W4Q - 1);
    const int qm4 = max(q - 4, 0), qp4 = min(q + 4, W4Q - 1);
    const bool pl4 = (q == 0), pr4 = (q == W4Q - 1);
    const bool pl16 = (q < 4), pr16 = (q > W4Q - 5);

#pragma unroll 1
    for (int step = 0; step < NSTEP; ++step) {
        const int h0 = row0 + step * SS;
        const int hr = h0 + g * 4;

        // Issue next band's (rows [h0+32, h0+48)) DMA loads FIRST.
        if (step < NSTEP - 1) {
#pragma unroll
            for (int k = 0; k < 4; ++k)
                STAGE_ROW(h0 + 32 + wr * 4 + k);
        }

        // d=16 vertical neighbors: direct GLOBAL loads (L2-hot: staged <=32
        // rows ago), issued early so latency hides under the LDS phase.
        // Values identical to the LDS-materialized clamped rows.
        f32x4 gu[4], gd[4];
#pragma unroll
        for (int r = 0; r < 4; ++r) {
            const int ru = max(hr + r - 16, 0);
            const int rd = min(hr + r + 16, HH - 1);
            gu[r] = img4[ru * W4Q + q];
            gd[r] = img4[rd * W4Q + q];
        }
        asm volatile("" ::: "memory");   // nt-stores stay issued AFTER the DMAs

        // ---- compute 4-row column run; d1/d4/horizontals from LDS
        f32x4 C[6];                          // rows hr-1 .. hr+4
#pragma unroll
        for (int k = 0; k < 6; ++k)
            C[k] = lds[((hr - 1 + k) & (NR - 1)) * RST + q];
        f32x4 U4[3], D4v[3];                 // d=4 extras
#pragma unroll
        for (int k = 0; k < 3; ++k)
            U4[k] = lds[((hr - 4 + k) & (NR - 1)) * RST + q];
#pragma unroll
        for (int k = 0; k < 3; ++k)
            D4v[k] = lds[((hr + 5 + k) & (NR - 1)) * RST + q];

#pragma unroll
        for (int r = 0; r < 4; ++r) {
            const int rs = ((hr + r) & (NR - 1)) * RST;
            f32x4 l4 = lds[rs + qm1];  if (pl4)  l4 = bc4(l4.x);
            f32x4 r4 = lds[rs + qp1];  if (pr4)  r4 = bc4(r4.w);
            f32x4 l16 = lds[rs + qm4]; if (pl16) l16 = bc4(l16.x);
            f32x4 r16 = lds[rs + qp4]; if (pr16) r16 = bc4(r16.w);

            const f32x4 cc = C[r + 1], up1 = C[r], dn1 = C[r + 2];
            const f32x4 u4 = (r < 3) ? U4[r] : C[0];        // row hr+r-4
            const f32x4 d4 = (r == 0) ? C[5] : D4v[r - 1];  // row hr+r+4

            // d=1 horizontal from registers (l4.w / r4.x are the +/-1 px)
            const f32x4 l1 = { l4.w, cc.x, cc.y, cc.z };
            const f32x4 r1 = { cc.y, cc.z, cc.w, r4.x };

            const f32x4 d1s  = (up1 + dn1) + (l1 + r1);
            const f32x4 d4s  = (u4 + d4) + (l4 + r4);
            const f32x4 d16s = (gu[r] + gd[r]) + (l16 + r16);

            f32x4 o;
#pragma unroll
            for (int j = 0; j < 4; ++j) {
                float acc = m4c * cc[j];
                acc = fmaf(s0, d1s[j], acc);
                acc = fmaf(s1, d4s[j], acc);
                acc = fmaf(s2, d16s[j], acc);
                o[j] = acc;
            }
            __builtin_nontemporal_store(o, out4 + (hr + r) * W4Q + q);
        }

        // Counted wait. Queue (issue order): [<=4 prev stores][4 DMAs]
        // [8 reg loads][4 new stores]. In-order decrement + the compiler's
        // own waits for gu/gd uses already confirm the DMAs; vmcnt(4) is the
        // conservative, known-correct release (<=4 new stores in flight).
        asm volatile("s_waitcnt vmcnt(4)" ::: "memory");
        __builtin_amdgcn_s_barrier();
        asm volatile("" ::: "memory");
    }
#undef STAGE_ROW
}

extern "C" void kernel_launch(void* const* d_in, const int* in_sizes, int n_in,
                              void* d_out, int out_size, void* d_ws, size_t ws_size,
                              hipStream_t stream) {
    const float* u = (const float*)d_in[0];
    const float* D = (const float*)d_in[1];
    float* out = (float*)d_out;

    lap3_kernel<<<512, 512, 0, stream>>>(u, D, out);
}

// Round 13
// 85.539 us; speedup vs baseline: 1.5324x; 1.5324x over previous
//
#include <hip/hip_runtime.h>
#include <math.h>

// Problem dims (fixed by the reference setup): B=4, C=64, H=512, W=512, fp32.
#define HH 512
#define W4Q 128          // float4 quads per row
#define IMG (HH * 512)
#define NR 64            // LDS ring: 64 row slots (pow2)
#define RST 129          // quads per slot (+1 pad -> odd stride, conflict-free)
#define SS 16            // rows per step (write slots disjoint from read span)
#define NSTEP (HH / SS)  // 32 steps: one block sweeps a whole image

typedef float f32x4 __attribute__((ext_vector_type(4)));

__device__ __forceinline__ f32x4 bc4(float v) { f32x4 r = {v, v, v, v}; return r; }
__device__ __forceinline__ float softplus(float x) {
    return fmaxf(x, 0.0f) + log1pf(expf(-fabsf(x)));
}

__global__ __launch_bounds__(512) void lap3_kernel(const float* __restrict__ u,
                                                   const float* __restrict__ D,
                                                   float* __restrict__ out) {
    // 132 KB rolling row window (64 rows x 129 quads). One block per CU.
    __shared__ f32x4 lds[NR * RST];

    const int bc = blockIdx.x;          // 256 blocks = one whole image each
    const int c  = bc & 63;

    const float s0 = softplus(D[c]);
    const float s1 = softplus(D[64 + c]);
    const float s2 = softplus(D[128 + c]);
    const float m4c = -4.0f * (s0 + s1 + s2);

    const int t    = threadIdx.x;
    const int q    = t & 127;           // compute: quad column
    const int g    = t >> 7;            // compute: row group 0..3 (4 rows each)
    const int lane = t & 63;            // lane within wave
    const int wave = t >> 6;            // 0..7
    const int hh   = wave & 1;          // staging: which 64-quad half-row
    const int wr   = wave >> 1;         // staging: row subgroup 0..3

    const f32x4* __restrict__ img4 =
        reinterpret_cast<const f32x4*>(u) + (size_t)bc * (IMG / 4);
    f32x4* __restrict__ out4 =
        reinterpret_cast<f32x4*>(out) + (size_t)bc * (IMG / 4);

    // per-lane global column base for direct-to-LDS staging
    const f32x4* gbase = img4 + hh * 64 + lane;

    // Direct global->LDS DMA: wave-uniform LDS base + lane*16B (linear layout;
    // the +1-quad pad lives at the END of each slot so halves stay contiguous).
#define STAGE_ROW(vrow_)                                                        \
    do {                                                                        \
        const int vr_ = (vrow_);                                                \
        const int cr_ = min(max(vr_, 0), HH - 1);                               \
        const int sl_ = vr_ & (NR - 1);                                         \
        __builtin_amdgcn_global_load_lds(                                       \
            (const __attribute__((address_space(1))) void*)(gbase + cr_ * W4Q), \
            (__attribute__((address_space(3))) void*)&lds[sl_ * RST + hh * 64], \
            16, 0, 0);                                                          \
    } while (0)

    // ---- prologue: stage virtual rows [-16, 32) (48 rows, top-clamped).
    // Vertical clamping is materialized here; compute has no vertical logic.
#pragma unroll
    for (int j = 0; j < 12; ++j)
        STAGE_ROW(-16 + wr + 4 * j);
    asm volatile("s_waitcnt vmcnt(0)" ::: "memory");
    __builtin_amdgcn_s_barrier();
    asm volatile("" ::: "memory");

    // horizontal boundary handling (validated R4/R7 scheme)
    const int qm1 = max(q - 1, 0), qp1 = min(q + 1, W4Q - 1);
    const int qm4 = max(q - 4, 0), qp4 = min(q + 4, W4Q - 1);
    const bool pl4 = (q == 0), pr4 = (q == W4Q - 1);
    const bool pl16 = (q < 4), pr16 = (q > W4Q - 5);

#pragma unroll 1
    for (int step = 0; step < NSTEP; ++step) {
        const int h0 = step * SS;

        // Issue next band's (rows [h0+32, h0+48)) DMA loads FIRST: they write
        // ring slots 48..63 ahead of the read-span start (rows [h0-16,h0+32)),
        // disjoint from all reads this step. HBM latency hides under compute.
        if (step < NSTEP - 1) {
#pragma unroll
            for (int k = 0; k < 4; ++k)
                STAGE_ROW(h0 + 32 + wr * 4 + k);   // only bottom clamp possible
        }
        asm volatile("" ::: "memory");   // keep nt-stores issued AFTER the DMAs

        // ---- compute 4-row column run, entirely from LDS
        const int hr = h0 + g * 4;
        f32x4 C[6];                          // rows hr-1 .. hr+4
#pragma unroll
        for (int k = 0; k < 6; ++k)
            C[k] = lds[((hr - 1 + k) & (NR - 1)) * RST + q];
        f32x4 U4[3], D4v[3];                 // d=4 extras
#pragma unroll
        for (int k = 0; k < 3; ++k)
            U4[k] = lds[((hr - 4 + k) & (NR - 1)) * RST + q];
#pragma unroll
        for (int k = 0; k < 3; ++k)
            D4v[k] = lds[((hr + 5 + k) & (NR - 1)) * RST + q];

#pragma unroll
        for (int r = 0; r < 4; ++r) {
            const int rs = ((hr + r) & (NR - 1)) * RST;
            f32x4 l4 = lds[rs + qm1];  if (pl4)  l4 = bc4(l4.x);
            f32x4 r4 = lds[rs + qp1];  if (pr4)  r4 = bc4(r4.w);
            f32x4 l16 = lds[rs + qm4]; if (pl16) l16 = bc4(l16.x);
            f32x4 r16 = lds[rs + qp4]; if (pr16) r16 = bc4(r16.w);
            const f32x4 u16 = lds[((hr + r - 16) & (NR - 1)) * RST + q];
            const f32x4 d16 = lds[((hr + r + 16) & (NR - 1)) * RST + q];

            const f32x4 cc = C[r + 1], up1 = C[r], dn1 = C[r + 2];
            const f32x4 u4 = (r < 3) ? U4[r] : C[0];        // row hr+r-4
            const f32x4 d4 = (r == 0) ? C[5] : D4v[r - 1];  // row hr+r+4

            // d=1 horizontal from registers (l4.w / r4.x are the +/-1 px)
            const f32x4 l1 = { l4.w, cc.x, cc.y, cc.z };
            const f32x4 r1 = { cc.y, cc.z, cc.w, r4.x };

            const f32x4 d1s  = (up1 + dn1) + (l1 + r1);
            const f32x4 d4s  = (u4 + d4) + (l4 + r4);
            const f32x4 d16s = (u16 + d16) + (l16 + r16);

            f32x4 o;
#pragma unroll
            for (int j = 0; j < 4; ++j) {
                float acc = m4c * cc[j];
                acc = fmaf(s0, d1s[j], acc);
                acc = fmaf(s1, d4s[j], acc);
                acc = fmaf(s2, d16s[j], acc);
                o[j] = acc;
            }
            __builtin_nontemporal_store(o, out4 + (hr + r) * W4Q + q);
        }

        // Counted wait. Per-wave VMEM queue (issue order):
        //   [<=4 leftover nt-stores, 4 staging DMAs, 4 nt-stores]
        // vmcnt(4) -> the 4 DMAs (ahead of this step's stores in the FIFO)
        // are complete; the new store tail stays in flight.
        asm volatile("s_waitcnt vmcnt(4)" ::: "memory");
        __builtin_amdgcn_s_barrier();
        asm volatile("" ::: "memory");
    }
#undef STAGE_ROW
}

extern "C" void kernel_launch(void* const* d_in, const int* in_sizes, int n_in,
                              void* d_out, int out_size, void* d_ws, size_t ws_size,
                              hipStream_t stream) {
    const float* u = (const float*)d_in[0];
    const float* D = (const float*)d_in[1];
    float* out = (float*)d_out;

    lap3_kernel<<<256, 512, 0, stream>>>(u, D, out);
}